// Round 1
// baseline (202.137 us; speedup 1.0000x reference)
//
#include <hip/hip_runtime.h>
#include <math.h>

#define TEMP_INV 10.0f   // 1/0.1
#define EPS 1e-8f
#define B_ 256
#define P_ 32
#define N_ 512
#define D_ 256
#define K_ (P_ + N_)     // 544

__device__ __forceinline__ float wave_reduce_sum(float v) {
    #pragma unroll
    for (int m = 32; m >= 1; m >>= 1) v += __shfl_xor(v, m, 64);
    return v;
}

__device__ __forceinline__ float wave_reduce_max(float v) {
    #pragma unroll
    for (int m = 32; m >= 1; m >>= 1) v = fmaxf(v, __shfl_xor(v, m, 64));
    return v;
}

// One wave per (b, k) row: coalesced float4 loads, 64 lanes x 16 B = D=256 floats.
__global__ __launch_bounds__(256) void sim_kernel(
    const float* __restrict__ anchors,
    const float* __restrict__ positives,
    const float* __restrict__ negatives,
    float* __restrict__ sim) {
    int gw   = blockIdx.x * 4 + (threadIdx.x >> 6);
    int lane = threadIdx.x & 63;
    if (gw >= B_ * K_) return;
    int b = gw / K_;
    int k = gw - b * K_;

    const float4* a4 = (const float4*)(anchors + (size_t)b * D_);
    const float4* s4 = (k < P_)
        ? (const float4*)(positives + ((size_t)b * P_ + k) * D_)
        : (const float4*)(negatives + ((size_t)b * N_ + (k - P_)) * D_);

    float4 a = a4[lane];
    float4 s = s4[lane];

    float dot = a.x * s.x + a.y * s.y + a.z * s.z + a.w * s.w;
    float ss  = s.x * s.x + s.y * s.y + s.z * s.z + s.w * s.w;
    float aa  = a.x * a.x + a.y * a.y + a.z * a.z + a.w * a.w;

    dot = wave_reduce_sum(dot);
    ss  = wave_reduce_sum(ss);
    aa  = wave_reduce_sum(aa);

    if (lane == 0) {
        float denom = fmaxf(sqrtf(aa) * sqrtf(ss), EPS);
        sim[gw] = dot / denom * TEMP_INV;
    }
}

// One block (256 threads = 4 waves) per batch row b: LSE + partial loss.
__global__ __launch_bounds__(256) void softmax_kernel(
    const float* __restrict__ sim,
    float* __restrict__ partials) {
    int b    = blockIdx.x;
    int tid  = threadIdx.x;
    int wid  = tid >> 6;
    int lane = tid & 63;
    const float* row = sim + (size_t)b * K_;

    // local values: K_=544 -> each thread holds up to 3
    float vals[3];
    int cnt = 0;
    float lmax = -INFINITY;
    for (int k = tid; k < K_; k += 256) {
        float v = row[k];
        vals[cnt++] = v;
        lmax = fmaxf(lmax, v);
    }

    __shared__ float s_max[4];
    __shared__ float s_sum[4];
    __shared__ float s_pos[4];

    float wmax = wave_reduce_max(lmax);
    if (lane == 0) s_max[wid] = wmax;
    __syncthreads();
    float bmax = fmaxf(fmaxf(s_max[0], s_max[1]), fmaxf(s_max[2], s_max[3]));

    float lsum = 0.0f;
    for (int i = 0; i < cnt; i++) lsum += expf(vals[i] - bmax);
    float wsum = wave_reduce_sum(lsum);
    if (lane == 0) s_sum[wid] = wsum;

    // sum of sim over first P columns: only first chunk (k = tid) can have k < P
    float lp = (tid < P_) ? vals[0] : 0.0f;
    float wp = wave_reduce_sum(lp);
    if (lane == 0) s_pos[wid] = wp;
    __syncthreads();

    if (tid == 0) {
        float bsum = s_sum[0] + s_sum[1] + s_sum[2] + s_sum[3];
        float bpos = s_pos[0] + s_pos[1] + s_pos[2] + s_pos[3];
        float lse  = bmax + logf(bsum);
        partials[b] = (float)P_ * lse - bpos;
    }
}

// Single block: reduce B_=256 partials -> scalar loss.
__global__ __launch_bounds__(256) void finalize_kernel(
    const float* __restrict__ partials,
    float* __restrict__ out) {
    int tid  = threadIdx.x;
    int wid  = tid >> 6;
    int lane = tid & 63;
    float v  = partials[tid];  // B_ == 256 == blockDim
    float ws = wave_reduce_sum(v);
    __shared__ float s[4];
    if (lane == 0) s[wid] = ws;
    __syncthreads();
    if (tid == 0) {
        out[0] = (s[0] + s[1] + s[2] + s[3]) / (float)(B_ * P_);
    }
}

extern "C" void kernel_launch(void* const* d_in, const int* in_sizes, int n_in,
                              void* d_out, int out_size, void* d_ws, size_t ws_size,
                              hipStream_t stream) {
    const float* anchors   = (const float*)d_in[0];
    const float* positives = (const float*)d_in[1];
    const float* negatives = (const float*)d_in[2];
    float* out      = (float*)d_out;
    float* sim      = (float*)d_ws;                 // B_*K_ floats
    float* partials = sim + (size_t)B_ * K_;        // B_ floats

    int n_rows   = B_ * K_;                         // 139264, divisible by 4
    int n_blocks = (n_rows + 3) / 4;                // 4 waves per block
    sim_kernel<<<n_blocks, 256, 0, stream>>>(anchors, positives, negatives, sim);
    softmax_kernel<<<B_, 256, 0, stream>>>(sim, partials);
    finalize_kernel<<<1, 256, 0, stream>>>(partials, out);
}

// Round 2
// 201.860 us; speedup vs baseline: 1.0014x; 1.0014x over previous
//
#include <hip/hip_runtime.h>
#include <math.h>

#define TEMP_INV 10.0f   // 1/0.1
#define EPS 1e-8f
#define B_ 256
#define P_ 32
#define N_ 512
#define D_ 256
#define K_ (P_ + N_)     // 544
#define G_ (K_ / 4)      // 136 groups of 4 samples per batch row

__device__ __forceinline__ float wave_reduce_sum(float v) {
    #pragma unroll
    for (int m = 32; m >= 1; m >>= 1) v += __shfl_xor(v, m, 64);
    return v;
}

__device__ __forceinline__ float wave_reduce_max(float v) {
    #pragma unroll
    for (int m = 32; m >= 1; m >>= 1) v = fmaxf(v, __shfl_xor(v, m, 64));
    return v;
}

__device__ __forceinline__ float dot4(float4 a, float4 b) {
    return a.x * b.x + a.y * b.y + a.z * b.z + a.w * b.w;
}

// One wave per (b, group-of-4-k): anchor loaded & reduced once per wave,
// 4 independent 1 KB sample loads in flight. 64 lanes x float4 = D=256.
__global__ __launch_bounds__(256) void sim_kernel(
    const float* __restrict__ anchors,
    const float* __restrict__ positives,
    const float* __restrict__ negatives,
    float* __restrict__ sim,
    float* __restrict__ out) {
    int gw   = blockIdx.x * 4 + (threadIdx.x >> 6);   // 0 .. B_*G_-1 exactly
    int lane = threadIdx.x & 63;
    int b  = gw / G_;
    int g  = gw - b * G_;
    int k0 = g * 4;

    const float4* a4 = (const float4*)(anchors + (size_t)b * D_);
    float4 a = a4[lane];

    // P_=32 divisible by 4: group is entirely positive or entirely negative
    const float4* base = (k0 < P_)
        ? (const float4*)(positives + ((size_t)b * P_ + k0) * D_)
        : (const float4*)(negatives + ((size_t)b * N_ + (k0 - P_)) * D_);

    float4 s0 = base[lane];
    float4 s1 = base[64 + lane];
    float4 s2 = base[128 + lane];
    float4 s3 = base[192 + lane];

    float na = sqrtf(wave_reduce_sum(dot4(a, a)));

    float d0 = wave_reduce_sum(dot4(a, s0));
    float q0 = wave_reduce_sum(dot4(s0, s0));
    float d1 = wave_reduce_sum(dot4(a, s1));
    float q1 = wave_reduce_sum(dot4(s1, s1));
    float d2 = wave_reduce_sum(dot4(a, s2));
    float q2 = wave_reduce_sum(dot4(s2, s2));
    float d3 = wave_reduce_sum(dot4(a, s3));
    float q3 = wave_reduce_sum(dot4(s3, s3));

    if (lane == 0) {
        float* row = sim + (size_t)b * K_ + k0;
        row[0] = d0 / fmaxf(na * sqrtf(q0), EPS) * TEMP_INV;
        row[1] = d1 / fmaxf(na * sqrtf(q1), EPS) * TEMP_INV;
        row[2] = d2 / fmaxf(na * sqrtf(q2), EPS) * TEMP_INV;
        row[3] = d3 / fmaxf(na * sqrtf(q3), EPS) * TEMP_INV;
    }

    // zero the (0xAA-poisoned) scalar output before softmax's atomics;
    // stream order guarantees this kernel completes before softmax starts.
    if (blockIdx.x == 0 && threadIdx.x == 0) out[0] = 0.0f;
}

// One block (256 threads = 4 waves) per batch row b: LSE + atomic loss add.
__global__ __launch_bounds__(256) void softmax_kernel(
    const float* __restrict__ sim,
    float* __restrict__ out) {
    int b    = blockIdx.x;
    int tid  = threadIdx.x;
    int wid  = tid >> 6;
    int lane = tid & 63;
    const float* row = sim + (size_t)b * K_;

    // K_=544 -> each thread holds up to 3 values
    float vals[3];
    int cnt = 0;
    float lmax = -INFINITY;
    for (int k = tid; k < K_; k += 256) {
        float v = row[k];
        vals[cnt++] = v;
        lmax = fmaxf(lmax, v);
    }

    __shared__ float s_max[4];
    __shared__ float s_sum[4];
    __shared__ float s_pos[4];

    float wmax = wave_reduce_max(lmax);
    if (lane == 0) s_max[wid] = wmax;
    __syncthreads();
    float bmax = fmaxf(fmaxf(s_max[0], s_max[1]), fmaxf(s_max[2], s_max[3]));

    float lsum = 0.0f;
    for (int i = 0; i < cnt; i++) lsum += expf(vals[i] - bmax);
    float wsum = wave_reduce_sum(lsum);
    if (lane == 0) s_sum[wid] = wsum;

    // sum of sim over first P columns: only k = tid chunk can have k < P
    float lp = (tid < P_) ? vals[0] : 0.0f;
    float wp = wave_reduce_sum(lp);
    if (lane == 0) s_pos[wid] = wp;
    __syncthreads();

    if (tid == 0) {
        float bsum = s_sum[0] + s_sum[1] + s_sum[2] + s_sum[3];
        float bpos = s_pos[0] + s_pos[1] + s_pos[2] + s_pos[3];
        float lse  = bmax + logf(bsum);
        float partial = ((float)P_ * lse - bpos) * (1.0f / (float)(B_ * P_));
        atomicAdd(out, partial);
    }
}

extern "C" void kernel_launch(void* const* d_in, const int* in_sizes, int n_in,
                              void* d_out, int out_size, void* d_ws, size_t ws_size,
                              hipStream_t stream) {
    const float* anchors   = (const float*)d_in[0];
    const float* positives = (const float*)d_in[1];
    const float* negatives = (const float*)d_in[2];
    float* out = (float*)d_out;
    float* sim = (float*)d_ws;                      // B_*K_ floats

    int n_waves  = B_ * G_;                         // 34816, divisible by 4
    int n_blocks = n_waves / 4;                     // 8704 blocks, 4 waves each
    sim_kernel<<<n_blocks, 256, 0, stream>>>(anchors, positives, negatives, sim, out);
    softmax_kernel<<<B_, 256, 0, stream>>>(sim, out);
}